// Round 10
// baseline (1029.484 us; speedup 1.0000x reference)
//
#include <hip/hip_runtime.h>

typedef _Float16 half8 __attribute__((ext_vector_type(8)));
typedef _Float16 half4 __attribute__((ext_vector_type(4)));
typedef float floatx4 __attribute__((ext_vector_type(4)));

template<int N> struct ic { static constexpr int value = N; };

__device__ __forceinline__ float fast_rcp(float x) { return __builtin_amdgcn_rcpf(x); }
__device__ __forceinline__ float fast_sigmoid(float x) { return fast_rcp(1.f + __expf(-x)); }
__device__ __forceinline__ float fast_tanh(float x) { return 1.f - 2.f*fast_rcp(1.f + __expf(2.f*x)); }

// ---------------- prep: fp16 fragment-ordered weights + bias sums + prog zero ----
__global__ void prep_kernel(const float* __restrict__ wih0, const float* __restrict__ whh0,
                            const float* __restrict__ bih0, const float* __restrict__ bhh0,
                            const float* __restrict__ wih1, const float* __restrict__ whh1,
                            const float* __restrict__ bih1, const float* __restrict__ bhh1,
                            _Float16* __restrict__ w0f, _Float16* __restrict__ w1f,
                            float* __restrict__ bias0, float* __restrict__ bias1,
                            int* __restrict__ prog)
{
  int stride = gridDim.x * blockDim.x;
  int idx0 = blockIdx.x * blockDim.x + threadIdx.x;
  const int N0 = 6*32*64*8;      // layer0: K=192 (x 64 | h 128)
  const int N1 = 8*32*64*8;      // layer1: K=256 (h1 128 | h 128)
  for (int e = idx0; e < N0 + N1 + 1024 + 128; e += stride) {
    if (e < N0) {
      int j = e & 7; int le = e >> 3; int lane = le & 63; int frag = le >> 6;
      int kt = frag >> 5, ntile = frag & 31;
      int n = ntile*16 + (lane & 15);
      int kk = kt*32 + ((lane >> 4) << 3) + j;
      float v = (kk < 64) ? wih0[n*64 + kk] : whh0[n*128 + (kk - 64)];
      w0f[e] = (_Float16)v;
    } else if (e < N0 + N1) {
      int e2 = e - N0;
      int j = e2 & 7; int le = e2 >> 3; int lane = le & 63; int frag = le >> 6;
      int kt = frag >> 5, ntile = frag & 31;
      int n = ntile*16 + (lane & 15);
      int kk = kt*32 + ((lane >> 4) << 3) + j;
      float v = (kk < 128) ? wih1[n*128 + kk] : whh1[n*128 + (kk - 128)];
      w1f[e2] = (_Float16)v;
    } else if (e < N0 + N1 + 1024) {
      int i = e - (N0 + N1);
      if (i < 512) bias0[i] = bih0[i] + bhh0[i];
      else         bias1[i - 512] = bih1[i - 512] + bhh1[i - 512];
    } else {
      prog[e - (N0 + N1 + 1024)] = 0;    // per-row-block progress flags
    }
  }
}

// ---------------- fused pipelined 2-layer LSTM ----------------
// Grid 256, block 512. Blocks 0..127: layer 0, rows 4b..4b+3; blocks 128..255:
// layer 1, same rows, lagged ~3 windows via prog[]. 1 block/CU (LDS ~93KB) ->
// all co-resident -> spin-wait deadlock-free. Block r and 128+r land on the
// SAME XCD (mod-8 round robin) -> after producer wbl2 the h1 lines are clean
// in the SHARED L2 -> handoff reads are L2-local (watch FETCH_SIZE drop).
// Handshake (round-9 fix): consumer polls with ACQUIRE RMW (fetch_add 0) --
// executes at the coherence point, always fresh (plain acquire loads were
// hitting a stale line in the consumer L2 -> serialization). Producer: after
// __syncthreads (all waves' flush stores drained to L2), tid0 __threadfence
// (wbl2) + RELEASE exchange.
// Padding (round-9 fix): preLDS en-stride 132 (m-row 2112B, rbi groups 16
// banks apart), hist row 136 halves (16B-aligned, rbi groups 4 banks apart).
__global__ __launch_bounds__(512, 2) void lstm_fused(const float* __restrict__ x,
    const _Float16* __restrict__ w0f, const float* __restrict__ bias0,
    const _Float16* __restrict__ w1f, const float* __restrict__ bias1,
    const float* __restrict__ wlin, const float* __restrict__ blin,
    _Float16* __restrict__ h1, int* __restrict__ prog,
    float* __restrict__ out)
{
  __shared__ __align__(16) char smem[95232];
  const int tid = threadIdx.x;
  const int lane = tid & 63;
  const int w = tid >> 6;
  const int role = blockIdx.x >> 7;
  const int rblk = blockIdx.x & 127;
  const int r0 = rblk * 4;
  int* pr = prog + rblk;

  const int li = lane & 15;
  const int en = w*16 + li;                 // column 0..127
  const int rbi = lane >> 4;                // block-row 0..3
  const bool arow = (lane & 3) == 0;        // A-frag carrier lanes (m=4*msl)
  const int aidx = ((lane >> 2) & 3)*4 + (lane >> 4);   // msl*4 + kgrp
  const int eoff = ((en>>5)*16 + rbi*4 + ((en&31)>>3))*8 + (en&7);

  // staging thread map: sdt = step-in-SW 0..7, srow = row 0..3
  const int sdt = tid >> 6, srow = (tid >> 4) & 3;
  const int sm = (sdt & 3)*4 + srow;        // A-frag m = dt*4 + row

  if (role == 0) {
    // ================= layer 0 =================
    float* preLDS   = (float*)smem;                   // [2][16m][132en][4g] = 67584B
    _Float16* aFh   = (_Float16*)(smem + 67584);      // [2 SW][4 fs][64][8] = 8KB
    half8* aF       = (half8*)aFh;
    half8* hA       = (half8*)(smem + 75776);         // [2][64] = 2KB
    _Float16* hist  = (_Float16*)(smem + 77824);      // [16][4][136] = 17408B

    ((int*)hA)[tid] = 0;

    half8 bf[6][4];                                   // 24 frags = 96 AGPR
#pragma unroll
    for (int kt = 0; kt < 6; ++kt)
#pragma unroll
      for (int g = 0; g < 4; ++g) {
        bf[kt][g] = *reinterpret_cast<const half8*>(w0f + (size_t)((kt*32 + g*8 + w)*64 + lane)*8);
        asm volatile("" : "+a"(bf[kt][g]));
      }
    float bias_v[4];
#pragma unroll
    for (int g = 0; g < 4; ++g) bias_v[g] = bias0[g*128 + en];

    const int scq = (tid & 15) * 4;                   // x col quad
    const int sfs = (sdt >> 2)*2 + (scq >> 5);        // fragset = pb*2 + kt
    const int sidx = (sfs*64 + ((((scq&31)>>3)<<4) | sm))*8 + (scq & 7);
    const int fr = tid >> 7, fdt = (tid >> 4) & 7, fn = (tid & 15)*8;

    // prologue: stage SW0, SW1
    {
      float4 v0 = *reinterpret_cast<const float4*>(x + ((size_t)(r0+srow)*512 + sdt)*64 + scq);
      float4 v1 = *reinterpret_cast<const float4*>(x + ((size_t)(r0+srow)*512 + 8 + sdt)*64 + scq);
      half4 h0 = {(_Float16)v0.x, (_Float16)v0.y, (_Float16)v0.z, (_Float16)v0.w};
      half4 h1v = {(_Float16)v1.x, (_Float16)v1.y, (_Float16)v1.z, (_Float16)v1.w};
      *reinterpret_cast<half4*>(aFh + sidx) = h0;
      *reinterpret_cast<half4*>(aFh + 2048 + sidx) = h1v;
    }
    __syncthreads();

    auto proj = [&](auto swb_t, auto pbl_t, auto slot_t) {
      constexpr int SWB = decltype(swb_t)::value;
      constexpr int PBL = decltype(pbl_t)::value;
      constexpr int SLOT = decltype(slot_t)::value;
      floatx4 accP[4];
#pragma unroll
      for (int g = 0; g < 4; ++g) { float bb = bias_v[g]; accP[g] = (floatx4){bb,bb,bb,bb}; }
#pragma unroll
      for (int kt = 0; kt < 2; ++kt) {
        half8 af = aF[SWB*256 + (PBL*2 + kt)*64 + lane];
#pragma unroll
        for (int g = 0; g < 4; ++g)
          accP[g] = __builtin_amdgcn_mfma_f32_16x16x32_f16(af, bf[kt][g], accP[g], 0, 0, 0);
      }
#pragma unroll
      for (int reg = 0; reg < 4; ++reg) {
        int m = (lane>>4)*4 + reg;
        floatx4 pv = (floatx4){accP[0][reg], accP[1][reg], accP[2][reg], accP[3][reg]};
        *reinterpret_cast<floatx4*>(&preLDS[SLOT*8448 + (m*132 + en)*4]) = pv;
      }
    };

    proj(ic<0>{}, ic<0>{}, ic<0>{});       // 4-batch 0 -> slot0

    half8 a0 = {}, a1 = {}, a2 = {}, a3 = {};
    float4 sv;
    float cst = 0.f;
    floatx4 acc[4];
#pragma unroll
    for (int g = 0; g < 4; ++g) acc[g] = (floatx4){0.f,0.f,0.f,0.f};
    floatx4 p4c = *reinterpret_cast<const floatx4*>(&preLDS[(rbi*132 + en)*4]);

    auto core = [&](auto tag) {
      constexpr int TM = decltype(tag)::value;        // 0..15 (window-pair step)
      constexpr int CUR = TM & 1;
      constexpr int SLN = ((TM + 1) >> 2) & 1;
      constexpr int DTN = (TM + 1) & 3;
      if (arow) {
        a0 = hA[CUR*64 +  0 + aidx];
        a1 = hA[CUR*64 + 16 + aidx];
        a2 = hA[CUR*64 + 32 + aidx];
        a3 = hA[CUR*64 + 48 + aidx];
      }
      acc[0][0] = p4c[0]; acc[1][0] = p4c[1]; acc[2][0] = p4c[2]; acc[3][0] = p4c[3];
#pragma unroll
      for (int g = 0; g < 4; ++g)
        acc[g] = __builtin_amdgcn_mfma_f32_16x16x32_f16(a0, bf[2][g], acc[g], 0, 0, 0);
#pragma unroll
      for (int g = 0; g < 4; ++g)
        acc[g] = __builtin_amdgcn_mfma_f32_16x16x32_f16(a1, bf[3][g], acc[g], 0, 0, 0);
#pragma unroll
      for (int g = 0; g < 4; ++g)
        acc[g] = __builtin_amdgcn_mfma_f32_16x16x32_f16(a2, bf[4][g], acc[g], 0, 0, 0);
#pragma unroll
      for (int g = 0; g < 4; ++g)
        acc[g] = __builtin_amdgcn_mfma_f32_16x16x32_f16(a3, bf[5][g], acc[g], 0, 0, 0);
      p4c = *reinterpret_cast<const floatx4*>(&preLDS[SLN*8448 + ((DTN*4 + rbi)*132 + en)*4]);
      float ii = fast_sigmoid(acc[0][0]);
      float ff = fast_sigmoid(acc[1][0]);
      float gg = fast_tanh(acc[2][0]);
      float oo = fast_sigmoid(acc[3][0]);
      cst = ff*cst + ii*gg;
      float hv2 = oo*fast_tanh(cst);
      _Float16 hh = (_Float16)hv2;
      ((_Float16*)hA)[(CUR^1)*512 + eoff] = hh;
      hist[TM*544 + rbi*136 + en] = hh;
    };

    auto window = [&](int B, auto wpar_t) {
      constexpr int WPAR = decltype(wpar_t)::value;
      __syncthreads();
      if (B >= 1) {                        // flush window B-1
        half8 v = *reinterpret_cast<const half8*>(&hist[((WPAR^1)*8 + fdt)*544 + fr*136 + fn]);
        *reinterpret_cast<half8*>(h1 + ((size_t)(r0+fr)*512 + (B-1)*8 + fdt)*128 + fn) = v;
      }
      proj(ic<WPAR>{}, ic<1>{}, ic<1>{});  // 4-batch 2B+1 -> slot1
      core(ic<WPAR*8 + 0>{});
      __syncthreads();                     // all waves' older stores drained here
      if (tid == 0 && B >= 1) {            // windows <= B-1 flushed & in L2
        __threadfence();                   // wbl2 -> IC (and clean lines stay in L2)
        __hip_atomic_exchange(pr, B, __ATOMIC_RELEASE, __HIP_MEMORY_SCOPE_AGENT);
      }
      if (B < 62)
        sv = *reinterpret_cast<const float4*>(x + ((size_t)(r0+srow)*512 + (B+2)*8 + sdt)*64 + scq);
      core(ic<WPAR*8 + 1>{});
      __syncthreads();
      core(ic<WPAR*8 + 2>{});
      __syncthreads();
      if (B < 62) {                        // write staged SW B+2 -> buf WPAR
        half4 hv = {(_Float16)sv.x, (_Float16)sv.y, (_Float16)sv.z, (_Float16)sv.w};
        *reinterpret_cast<half4*>(aFh + WPAR*2048 + sidx) = hv;
      }
      core(ic<WPAR*8 + 3>{});
      __syncthreads();
      if (B < 63) proj(ic<WPAR^1>{}, ic<0>{}, ic<0>{});  // 4-batch 2B+2 -> slot0
      core(ic<WPAR*8 + 4>{});
      __syncthreads(); core(ic<WPAR*8 + 5>{});
      __syncthreads(); core(ic<WPAR*8 + 6>{});
      __syncthreads(); core(ic<WPAR*8 + 7>{});
    };

    for (int bp = 0; bp < 32; ++bp) {
      window(2*bp,     ic<0>{});
      window(2*bp + 1, ic<1>{});
    }
    __syncthreads();
    {                                      // final flush: window 63 (slots 8..15)
      half8 v = *reinterpret_cast<const half8*>(&hist[(8 + fdt)*544 + fr*136 + fn]);
      *reinterpret_cast<half8*>(h1 + ((size_t)(r0+fr)*512 + 504 + fdt)*128 + fn) = v;
    }
    __syncthreads();                       // drain final flush
    if (tid == 0) {
      __threadfence();
      __hip_atomic_exchange(pr, 64, __ATOMIC_RELEASE, __HIP_MEMORY_SCOPE_AGENT);
    }
  } else {
    // ================= layer 1 (lagged consumer) =================
    float* preLDS   = (float*)smem;                   // 67584B (padded 132)
    _Float16* aFh   = (_Float16*)(smem + 67584);      // [2 SW][8 fs][64][8] = 16KB
    half8* aF       = (half8*)aFh;
    half8* hA       = (half8*)(smem + 83968);         // 2KB
    float* head     = (float*)(smem + 86016);         // 2KB

    ((int*)hA)[tid] = 0;

    half8 bf[8][4];                                   // 32 frags = 128 AGPR
#pragma unroll
    for (int kt = 0; kt < 8; ++kt)
#pragma unroll
      for (int g = 0; g < 4; ++g) {
        bf[kt][g] = *reinterpret_cast<const half8*>(w1f + (size_t)((kt*32 + g*8 + w)*64 + lane)*8);
        asm volatile("" : "+a"(bf[kt][g]));
      }
    float bias_v[4];
#pragma unroll
    for (int g = 0; g < 4; ++g) bias_v[g] = bias1[g*128 + en];

    const int sc8 = (tid & 15) * 8;                   // h1 col octet
    const int sfs = (sdt >> 2)*4 + (sc8 >> 5);        // fragset = pb*4 + kt
    const int sidx = (sfs*64 + ((((sc8&31)>>3)<<4) | sm))*8;
    const float wl = wlin[en];

    // prologue: wait for l0 windows 0,1 (ACQUIRE RMW poll: always fresh)
    if (lane == 0)
      while (__hip_atomic_fetch_add(pr, 0, __ATOMIC_ACQUIRE, __HIP_MEMORY_SCOPE_AGENT) < 2)
        __builtin_amdgcn_s_sleep(16);
    __syncthreads();
    {
      uint4 v0 = *reinterpret_cast<const uint4*>(h1 + ((size_t)(r0+srow)*512 + sdt)*128 + sc8);
      uint4 v1 = *reinterpret_cast<const uint4*>(h1 + ((size_t)(r0+srow)*512 + 8 + sdt)*128 + sc8);
      *reinterpret_cast<uint4*>(aFh + sidx) = v0;
      *reinterpret_cast<uint4*>(aFh + 4096 + sidx) = v1;
    }
    __syncthreads();

    auto proj = [&](auto swb_t, auto pbl_t, auto slot_t) {
      constexpr int SWB = decltype(swb_t)::value;
      constexpr int PBL = decltype(pbl_t)::value;
      constexpr int SLOT = decltype(slot_t)::value;
      floatx4 accP[4];
#pragma unroll
      for (int g = 0; g < 4; ++g) { float bb = bias_v[g]; accP[g] = (floatx4){bb,bb,bb,bb}; }
#pragma unroll
      for (int kt = 0; kt < 4; ++kt) {
        half8 af = aF[SWB*512 + (PBL*4 + kt)*64 + lane];
#pragma unroll
        for (int g = 0; g < 4; ++g)
          accP[g] = __builtin_amdgcn_mfma_f32_16x16x32_f16(af, bf[kt][g], accP[g], 0, 0, 0);
      }
#pragma unroll
      for (int reg = 0; reg < 4; ++reg) {
        int m = (lane>>4)*4 + reg;
        floatx4 pv = (floatx4){accP[0][reg], accP[1][reg], accP[2][reg], accP[3][reg]};
        *reinterpret_cast<floatx4*>(&preLDS[SLOT*8448 + (m*132 + en)*4]) = pv;
      }
    };

    proj(ic<0>{}, ic<0>{}, ic<0>{});       // 4-batch 0 -> slot0

    half8 a0 = {}, a1 = {}, a2 = {}, a3 = {};
    uint4 sv;
    float cst = 0.f, hl = 0.f;
    floatx4 acc[4];
#pragma unroll
    for (int g = 0; g < 4; ++g) acc[g] = (floatx4){0.f,0.f,0.f,0.f};
    floatx4 p4c = *reinterpret_cast<const floatx4*>(&preLDS[(rbi*132 + en)*4]);

    auto core = [&](auto tag) {
      constexpr int TM = decltype(tag)::value;
      constexpr int CUR = TM & 1;
      constexpr int SLN = ((TM + 1) >> 2) & 1;
      constexpr int DTN = (TM + 1) & 3;
      if (arow) {
        a0 = hA[CUR*64 +  0 + aidx];
        a1 = hA[CUR*64 + 16 + aidx];
        a2 = hA[CUR*64 + 32 + aidx];
        a3 = hA[CUR*64 + 48 + aidx];
      }
      acc[0][0] = p4c[0]; acc[1][0] = p4c[1]; acc[2][0] = p4c[2]; acc[3][0] = p4c[3];
#pragma unroll
      for (int g = 0; g < 4; ++g)
        acc[g] = __builtin_amdgcn_mfma_f32_16x16x32_f16(a0, bf[4][g], acc[g], 0, 0, 0);
#pragma unroll
      for (int g = 0; g < 4; ++g)
        acc[g] = __builtin_amdgcn_mfma_f32_16x16x32_f16(a1, bf[5][g], acc[g], 0, 0, 0);
#pragma unroll
      for (int g = 0; g < 4; ++g)
        acc[g] = __builtin_amdgcn_mfma_f32_16x16x32_f16(a2, bf[6][g], acc[g], 0, 0, 0);
#pragma unroll
      for (int g = 0; g < 4; ++g)
        acc[g] = __builtin_amdgcn_mfma_f32_16x16x32_f16(a3, bf[7][g], acc[g], 0, 0, 0);
      p4c = *reinterpret_cast<const floatx4*>(&preLDS[SLN*8448 + ((DTN*4 + rbi)*132 + en)*4]);
      float ii = fast_sigmoid(acc[0][0]);
      float ff = fast_sigmoid(acc[1][0]);
      float gg = fast_tanh(acc[2][0]);
      float oo = fast_sigmoid(acc[3][0]);
      cst = ff*cst + ii*gg;
      hl = oo*fast_tanh(cst);
      ((_Float16*)hA)[(CUR^1)*512 + eoff] = (_Float16)hl;
    };

    auto window = [&](int B, auto wpar_t) {
      constexpr int WPAR = decltype(wpar_t)::value;
      __syncthreads();
      proj(ic<WPAR>{}, ic<1>{}, ic<1>{});  // 4-batch 2B+1 -> slot1
      core(ic<WPAR*8 + 0>{});
      __syncthreads();
      if (B < 62) {                        // gate on producer (ACQUIRE RMW), then stage
        if (lane == 0)
          while (__hip_atomic_fetch_add(pr, 0, __ATOMIC_ACQUIRE, __HIP_MEMORY_SCOPE_AGENT) < B + 3)
            __builtin_amdgcn_s_sleep(8);
        sv = *reinterpret_cast<const uint4*>(h1 + ((size_t)(r0+srow)*512 + (B+2)*8 + sdt)*128 + sc8);
      }
      core(ic<WPAR*8 + 1>{});
      __syncthreads();
      core(ic<WPAR*8 + 2>{});
      __syncthreads();
      if (B < 62)
        *reinterpret_cast<uint4*>(aFh + WPAR*4096 + sidx) = sv;
      core(ic<WPAR*8 + 3>{});
      __syncthreads();
      if (B < 63) proj(ic<WPAR^1>{}, ic<0>{}, ic<0>{});  // 4-batch 2B+2 -> slot0
      core(ic<WPAR*8 + 4>{});
      __syncthreads(); core(ic<WPAR*8 + 5>{});
      __syncthreads(); core(ic<WPAR*8 + 6>{});
      __syncthreads(); core(ic<WPAR*8 + 7>{});
    };

    for (int bp = 0; bp < 32; ++bp) {
      window(2*bp,     ic<0>{});
      window(2*bp + 1, ic<1>{});
    }

    // fused head: out[r0+rbi] = sum_en h_last * wlin + blin
    __syncthreads();
    head[rbi*128 + en] = hl * wl;
    __syncthreads();
    if (tid < 4) {
      float s = blin[0];
      for (int n = 0; n < 128; ++n) s += head[tid*128 + n];
      out[r0 + tid] = s;
    }
  }
}

extern "C" void kernel_launch(void* const* d_in, const int* in_sizes, int n_in,
                              void* d_out, int out_size, void* d_ws, size_t ws_size,
                              hipStream_t stream)
{
  const float* x    = (const float*)d_in[0];
  const float* wih0 = (const float*)d_in[1];
  const float* whh0 = (const float*)d_in[2];
  const float* bih0 = (const float*)d_in[3];
  const float* bhh0 = (const float*)d_in[4];
  const float* wih1 = (const float*)d_in[5];
  const float* whh1 = (const float*)d_in[6];
  const float* bih1 = (const float*)d_in[7];
  const float* bhh1 = (const float*)d_in[8];
  const float* wlin = (const float*)d_in[9];
  const float* blin = (const float*)d_in[10];
  float* out = (float*)d_out;

  char* ws = (char*)d_ws;
  _Float16* w0f = (_Float16*)(ws);               // 196608 B
  _Float16* w1f = (_Float16*)(ws + 196608);      // 262144 B
  float* bias0  = (float*)(ws + 458752);         // 2048 B
  float* bias1  = (float*)(ws + 460800);         // 2048 B
  int* prog     = (int*)(ws + 524288);           // 512 B progress flags
  _Float16* h1  = (_Float16*)(ws + 1048576);     // 64 MB inter-layer buffer

  prep_kernel<<<256, 256, 0, stream>>>(wih0, whh0, bih0, bhh0, wih1, whh1, bih1, bhh1,
                                       w0f, w1f, bias0, bias1, prog);
  lstm_fused<<<256, 512, 0, stream>>>(x, w0f, bias0, w1f, bias1, wlin, blin, h1, prog, out);
}

// Round 11
// 674.923 us; speedup vs baseline: 1.5253x; 1.5253x over previous
//
#include <hip/hip_runtime.h>

typedef _Float16 half8 __attribute__((ext_vector_type(8)));
typedef _Float16 half4 __attribute__((ext_vector_type(4)));
typedef _Float16 half2v __attribute__((ext_vector_type(2)));
typedef float floatx4 __attribute__((ext_vector_type(4)));

template<int N> struct ic { static constexpr int value = N; };

__device__ __forceinline__ float fast_rcp(float x) { return __builtin_amdgcn_rcpf(x); }
__device__ __forceinline__ float fast_sigmoid(float x) {
  return fast_rcp(1.f + __expf(-x));
}
__device__ __forceinline__ float fast_tanh(float x) {
  return 1.f - 2.f * fast_rcp(1.f + __expf(2.f * x));
}

// ---------------- prep: fp16 fragment-ordered weights + bias sums ----------------
// B-frag layout for mfma_f32_16x16x32_f16: lane L, reg j holds
// W[n = ntile*16 + (L&15)][k = ktile*32 + (L>>4)*8 + j].
// Buffer: [ktile][ntile(32)][lane(64)][8 f16]. Verified correct across all rounds.
__global__ void prep_kernel(const float* __restrict__ wih0, const float* __restrict__ whh0,
                            const float* __restrict__ bih0, const float* __restrict__ bhh0,
                            const float* __restrict__ wih1, const float* __restrict__ whh1,
                            const float* __restrict__ bih1, const float* __restrict__ bhh1,
                            _Float16* __restrict__ w0f, _Float16* __restrict__ w1f,
                            float* __restrict__ bias0, float* __restrict__ bias1)
{
  int stride = gridDim.x * blockDim.x;
  int idx0 = blockIdx.x * blockDim.x + threadIdx.x;
  const int N0 = 6*32*64*8;      // layer0: K=192 (x 64 | h 128)
  const int N1 = 8*32*64*8;      // layer1: K=256 (h1 128 | h 128)
  for (int e = idx0; e < N0 + N1 + 1024; e += stride) {
    if (e < N0) {
      int j = e & 7; int le = e >> 3; int lane = le & 63; int frag = le >> 6;
      int kt = frag >> 5, ntile = frag & 31;
      int n = ntile*16 + (lane & 15);
      int kk = kt*32 + ((lane >> 4) << 3) + j;
      float v = (kk < 64) ? wih0[n*64 + kk] : whh0[n*128 + (kk - 64)];
      w0f[e] = (_Float16)v;
    } else if (e < N0 + N1) {
      int e2 = e - N0;
      int j = e2 & 7; int le = e2 >> 3; int lane = le & 63; int frag = le >> 6;
      int kt = frag >> 5, ntile = frag & 31;
      int n = ntile*16 + (lane & 15);
      int kk = kt*32 + ((lane >> 4) << 3) + j;
      float v = (kk < 128) ? wih1[n*128 + kk] : whh1[n*128 + (kk - 128)];
      w1f[e2] = (_Float16)v;
    } else {
      int i = e - (N0 + N1);
      if (i < 512) bias0[i] = bih0[i] + bhh0[i];
      else         bias1[i - 512] = bih1[i - 512] + bhh1[i - 512];
    }
  }
}

// ---------------- layer 0 ----------------
// Best verified structure (round 6, 674 us): all weights AGPR-resident, 8 waves,
// 2 rows/block, one __syncthreads per step, T14 stage split, batched input
// projection, TM-specialized 16-step window pairs (every LDS offset immediate),
// persistent accumulator with element-0-only reseed, p4 prefetched one step
// ahead. Rounds 7-10 falsified: raw asm barriers (fragment scheduling regions),
// __builtin_exp2f (denormal fixup code), cross-CU producer/consumer pipeline
// (serializes), 2-blocks/CU (register arithmetic forbids weight residency).
__global__ __launch_bounds__(512, 2) void lstm_l0(const float* __restrict__ x,
    const _Float16* __restrict__ w0f, const float* __restrict__ bias0,
    _Float16* __restrict__ h1out)
{
  const int tid = threadIdx.x;
  const int lane = tid & 63;
  const int w = tid >> 6;
  const int r0 = blockIdx.x * 2;

  __shared__ float preLDS[2][8192];       // 2 x 32 KB pre-activation buffers
  __shared__ half8 aF[2][2*64];           // input A-frags, 2 ktiles (K=64)
  __shared__ half8 hA[2][4*8];            // compact recurrent frags (1 KB)
  __shared__ _Float16 hist[16][2][128];   // h history ring (8 KB)

  for (int i = tid; i < 2*4*8*4; i += 512) ((int*)hA)[i] = 0;

  half8 bf[6][4];                         // 24 frags = 96 AGPRs
#pragma unroll
  for (int kt = 0; kt < 6; ++kt)
#pragma unroll
    for (int g = 0; g < 4; ++g) {
      int frag = kt*32 + (g*8 + w);
      bf[kt][g] = *reinterpret_cast<const half8*>(w0f + (size_t)(frag*64 + lane)*8);
      asm volatile("" : "+a"(bf[kt][g]));
    }
  float bias_v[4];
#pragma unroll
  for (int g = 0; g < 4; ++g) bias_v[g] = bias0[g*128 + w*16 + (lane & 15)];

  // staging: thread -> (dt, r, col-pair); full A-frag half index
  const int sdt = tid >> 6, sr = (tid >> 5) & 1, scp = (tid & 31) * 2;
  const int sm = sdt*2 + sr;
  const int sidx = ((scp>>5)*64 + sm + (((scp&31)>>3)<<4))*8 + (scp & 7);

  const bool arow = (lane & 11) == 0;
  const int cIdx = ((lane >> 4) << 1) | ((lane >> 2) & 1);
  const int rb = lane >> 4;
  const int en = w*16 + (lane & 15);
  const int eoff = ((en>>5)*8 + ((en&31)>>3)*2 + rb)*8 + (en&7);
  // flush mapping (hoisted)
  const int fr = tid >> 8, rest = tid & 255;
  const int fdt = rest >> 5, fn = (rest & 31) * 4;
  float cst = 0.f;

  // prologue: stage batches 0 and 1
  {
    float2 v0 = *reinterpret_cast<const float2*>(x + ((size_t)(r0+sr)*512 + sdt)*64 + scp);
    float2 v1 = *reinterpret_cast<const float2*>(x + ((size_t)(r0+sr)*512 + 8 + sdt)*64 + scp);
    half2v h0; h0[0] = (_Float16)v0.x; h0[1] = (_Float16)v0.y;
    half2v h1v; h1v[0] = (_Float16)v1.x; h1v[1] = (_Float16)v1.y;
    *reinterpret_cast<half2v*>(((_Float16*)aF[0]) + sidx) = h0;
    *reinterpret_cast<half2v*>(((_Float16*)aF[1]) + sidx) = h1v;
  }
  __syncthreads();
  {                                        // pre[batch0] -> preLDS[0]
    floatx4 accP[4];
#pragma unroll
    for (int g = 0; g < 4; ++g) { float bb = bias_v[g]; accP[g] = (floatx4){bb,bb,bb,bb}; }
#pragma unroll
    for (int kt = 0; kt < 2; ++kt) {
      half8 af = aF[0][kt*64 + lane];
#pragma unroll
      for (int g = 0; g < 4; ++g)
        accP[g] = __builtin_amdgcn_mfma_f32_16x16x32_f16(af, bf[kt][g], accP[g], 0, 0, 0);
    }
#pragma unroll
    for (int reg = 0; reg < 4; ++reg) {
      int m = ((lane>>4)<<2) + reg;
      floatx4 pv = (floatx4){accP[0][reg], accP[1][reg], accP[2][reg], accP[3][reg]};
      *reinterpret_cast<floatx4*>(&preLDS[0][(m*128 + en)*4]) = pv;
    }
  }

  half8 a2 = {}, a3 = {}, a4 = {}, a5 = {};
  float2 sv;
  floatx4 acc[4];
#pragma unroll
  for (int g = 0; g < 4; ++g) acc[g] = (floatx4){0.f,0.f,0.f,0.f};

  floatx4 p4c = (floatx4){0.f,0.f,0.f,0.f};
  if (lane < 32)
    p4c = *reinterpret_cast<const floatx4*>(&preLDS[0][(rb*128 + en)*4]);

  auto core = [&](auto tag) {
    constexpr int TM = decltype(tag)::value;   // t & 15
    constexpr int CUR = TM & 1;
    constexpr int TN = (TM + 1) & 15;
    if (arow) {
      a2 = hA[CUR][ 0 + cIdx];
      a3 = hA[CUR][ 8 + cIdx];
      a4 = hA[CUR][16 + cIdx];
      a5 = hA[CUR][24 + cIdx];
    }
    acc[0][0] = p4c[0]; acc[1][0] = p4c[1]; acc[2][0] = p4c[2]; acc[3][0] = p4c[3];
#pragma unroll
    for (int g = 0; g < 4; ++g)
      acc[g] = __builtin_amdgcn_mfma_f32_16x16x32_f16(a2, bf[2][g], acc[g], 0, 0, 0);
#pragma unroll
    for (int g = 0; g < 4; ++g)
      acc[g] = __builtin_amdgcn_mfma_f32_16x16x32_f16(a3, bf[3][g], acc[g], 0, 0, 0);
#pragma unroll
    for (int g = 0; g < 4; ++g)
      acc[g] = __builtin_amdgcn_mfma_f32_16x16x32_f16(a4, bf[4][g], acc[g], 0, 0, 0);
#pragma unroll
    for (int g = 0; g < 4; ++g)
      acc[g] = __builtin_amdgcn_mfma_f32_16x16x32_f16(a5, bf[5][g], acc[g], 0, 0, 0);
    if (lane < 32) {
      // prefetch next step's pre-activation (constant offsets; latency hidden
      // under the transcendental chain + next barrier's lgkm drain)
      p4c = *reinterpret_cast<const floatx4*>(
          &preLDS[TN >> 3][((((TN & 7) << 1) + rb)*128 + en)*4]);
      float ii = fast_sigmoid(acc[0][0]);
      float ff = fast_sigmoid(acc[1][0]);
      float gg = fast_tanh(acc[2][0]);
      float oo = fast_sigmoid(acc[3][0]);
      cst = ff*cst + ii*gg;
      float hv2 = oo*fast_tanh(cst);
      _Float16 hh = (_Float16)hv2;
      ((_Float16*)hA[CUR^1])[eoff] = hh;
      hist[TM][rb][en] = hh;
    }
  };

  auto window = [&](int B, auto slot_tag) {
    constexpr int SLOT = decltype(slot_tag)::value;
    __syncthreads();
    if (B < 62)                            // T14: issue stage load (batch B+2)
      sv = *reinterpret_cast<const float2*>(x + ((size_t)(r0+sr)*512 + (B+2)*8 + sdt)*64 + scp);
    if (B >= 1) {                          // coalesced flush of prev window
      int tbase = (B-1)*8;
      half4 v = *reinterpret_cast<const half4*>(&hist[((SLOT^1)<<3) + fdt][fr][fn]);
      *reinterpret_cast<half4*>(h1out + ((size_t)(r0+fr)*512 + tbase + fdt)*128 + fn) = v;
    }
    if (B < 63) {                          // project batch B+1 -> preLDS[SLOT^1]
      floatx4 accP[4];
#pragma unroll
      for (int g = 0; g < 4; ++g) { float bb = bias_v[g]; accP[g] = (floatx4){bb,bb,bb,bb}; }
#pragma unroll
      for (int kt = 0; kt < 2; ++kt) {
        half8 af = aF[SLOT^1][kt*64 + lane];
#pragma unroll
        for (int g = 0; g < 4; ++g)
          accP[g] = __builtin_amdgcn_mfma_f32_16x16x32_f16(af, bf[kt][g], accP[g], 0, 0, 0);
      }
#pragma unroll
      for (int reg = 0; reg < 4; ++reg) {
        int m = ((lane>>4)<<2) + reg;
        floatx4 pv = (floatx4){accP[0][reg], accP[1][reg], accP[2][reg], accP[3][reg]};
        *reinterpret_cast<floatx4*>(&preLDS[SLOT^1][(m*128 + en)*4]) = pv;
      }
    }
    core(ic<SLOT*8 + 0>{});
    __syncthreads();
    if (B < 62) {                          // T14: LDS-write of stashed batch
      half2v hv; hv[0] = (_Float16)sv.x; hv[1] = (_Float16)sv.y;
      *reinterpret_cast<half2v*>(((_Float16*)aF[SLOT]) + sidx) = hv;
    }
    core(ic<SLOT*8 + 1>{});
    __syncthreads(); core(ic<SLOT*8 + 2>{});
    __syncthreads(); core(ic<SLOT*8 + 3>{});
    __syncthreads(); core(ic<SLOT*8 + 4>{});
    __syncthreads(); core(ic<SLOT*8 + 5>{});
    __syncthreads(); core(ic<SLOT*8 + 6>{});
    __syncthreads(); core(ic<SLOT*8 + 7>{});
  };

  for (int bp = 0; bp < 32; ++bp) {
    window(2*bp,     ic<0>{});
    window(2*bp + 1, ic<1>{});
  }
  __syncthreads();
  {                                        // final flush: steps 504..511
    half4 v = *reinterpret_cast<const half4*>(&hist[8 + fdt][fr][fn]);
    *reinterpret_cast<half4*>(h1out + ((size_t)(r0+fr)*512 + 504 + fdt)*128 + fn) = v;
  }
}

// ---------------- layer 1: K_in = 128 (4 ktiles), fused linear head ----------------
__global__ __launch_bounds__(512, 2) void lstm_l1(const _Float16* __restrict__ h1in,
    const _Float16* __restrict__ w1f, const float* __restrict__ bias1,
    const float* __restrict__ wlin, const float* __restrict__ blin,
    float* __restrict__ out)
{
  const int tid = threadIdx.x;
  const int lane = tid & 63;
  const int w = tid >> 6;
  const int r0 = blockIdx.x * 2;

  __shared__ float preLDS[2][8192];       // 2 x 32 KB
  __shared__ half8 aF[2][4*64];           // input A-frags, 4 ktiles (K=128)
  __shared__ half8 hA[2][4*8];
  __shared__ float head[256];

  for (int i = tid; i < 2*4*8*4; i += 512) ((int*)hA)[i] = 0;

  half8 bf[8][4];                         // 32 frags = 128 AGPRs
#pragma unroll
  for (int kt = 0; kt < 8; ++kt)
#pragma unroll
    for (int g = 0; g < 4; ++g) {
      int frag = kt*32 + (g*8 + w);
      bf[kt][g] = *reinterpret_cast<const half8*>(w1f + (size_t)(frag*64 + lane)*8);
      asm volatile("" : "+a"(bf[kt][g]));
    }
  float bias_v[4];
#pragma unroll
  for (int g = 0; g < 4; ++g) bias_v[g] = bias1[g*128 + w*16 + (lane & 15)];

  // staging: thread -> (dt, r, col-quad); fp16 passthrough (8B)
  const int sdt = tid >> 6, sr = (tid >> 5) & 1, scq = (tid & 31) * 4;
  const int sm = sdt*2 + sr;
  const int sidx = ((scq>>5)*64 + sm + (((scq&31)>>3)<<4))*8 + (scq & 7);

  const bool arow = (lane & 11) == 0;
  const int cIdx = ((lane >> 4) << 1) | ((lane >> 2) & 1);
  const int rb = lane >> 4;
  const int en = w*16 + (lane & 15);
  const int eoff = ((en>>5)*8 + ((en&31)>>3)*2 + rb)*8 + (en&7);
  const float wl = (lane < 32) ? wlin[en] : 0.f;
  float cst = 0.f;
  float hl = 0.f;

  // prologue: stage batches 0 and 1
  {
    uint2 v0 = *reinterpret_cast<const uint2*>(h1in + ((size_t)(r0+sr)*512 + sdt)*128 + scq);
    uint2 v1 = *reinterpret_cast<const uint2*>(h1in + ((size_t)(r0+sr)*512 + 8 + sdt)*128 + scq);
    *reinterpret_cast<uint2*>(((_Float16*)aF[0]) + sidx) = v0;
    *reinterpret_cast<uint2*>(((_Float16*)aF[1]) + sidx) = v1;
  }
  __syncthreads();
  {                                        // pre[batch0] -> preLDS[0]
    floatx4 accP[4];
#pragma unroll
    for (int g = 0; g < 4; ++g) { float bb = bias_v[g]; accP[g] = (floatx4){bb,bb,bb,bb}; }
#pragma unroll
    for (int kt = 0; kt < 4; ++kt) {
      half8 af = aF[0][kt*64 + lane];
#pragma unroll
      for (int g = 0; g < 4; ++g)
        accP[g] = __builtin_amdgcn_mfma_f32_16x16x32_f16(af, bf[kt][g], accP[g], 0, 0, 0);
    }
#pragma unroll
    for (int reg = 0; reg < 4; ++reg) {
      int m = ((lane>>4)<<2) + reg;
      floatx4 pv = (floatx4){accP[0][reg], accP[1][reg], accP[2][reg], accP[3][reg]};
      *reinterpret_cast<floatx4*>(&preLDS[0][(m*128 + en)*4]) = pv;
    }
  }

  half8 a4 = {}, a5 = {}, a6 = {}, a7 = {};
  uint2 sv;
  floatx4 acc[4];
#pragma unroll
  for (int g = 0; g < 4; ++g) acc[g] = (floatx4){0.f,0.f,0.f,0.f};

  floatx4 p4c = (floatx4){0.f,0.f,0.f,0.f};
  if (lane < 32)
    p4c = *reinterpret_cast<const floatx4*>(&preLDS[0][(rb*128 + en)*4]);

  auto core = [&](auto tag) {
    constexpr int TM = decltype(tag)::value;   // t & 15
    constexpr int CUR = TM & 1;
    constexpr int TN = (TM + 1) & 15;
    if (arow) {
      a4 = hA[CUR][ 0 + cIdx];
      a5 = hA[CUR][ 8 + cIdx];
      a6 = hA[CUR][16 + cIdx];
      a7 = hA[CUR][24 + cIdx];
    }
    acc[0][0] = p4c[0]; acc[1][0] = p4c[1]; acc[2][0] = p4c[2]; acc[3][0] = p4c[3];
#pragma unroll
    for (int g = 0; g < 4; ++g)
      acc[g] = __builtin_amdgcn_mfma_f32_16x16x32_f16(a4, bf[4][g], acc[g], 0, 0, 0);
#pragma unroll
    for (int g = 0; g < 4; ++g)
      acc[g] = __builtin_amdgcn_mfma_f32_16x16x32_f16(a5, bf[5][g], acc[g], 0, 0, 0);
#pragma unroll
    for (int g = 0; g < 4; ++g)
      acc[g] = __builtin_amdgcn_mfma_f32_16x16x32_f16(a6, bf[6][g], acc[g], 0, 0, 0);
#pragma unroll
    for (int g = 0; g < 4; ++g)
      acc[g] = __builtin_amdgcn_mfma_f32_16x16x32_f16(a7, bf[7][g], acc[g], 0, 0, 0);
    if (lane < 32) {
      p4c = *reinterpret_cast<const floatx4*>(
          &preLDS[TN >> 3][((((TN & 7) << 1) + rb)*128 + en)*4]);
      float ii = fast_sigmoid(acc[0][0]);
      float ff = fast_sigmoid(acc[1][0]);
      float gg = fast_tanh(acc[2][0]);
      float oo = fast_sigmoid(acc[3][0]);
      cst = ff*cst + ii*gg;
      hl = oo*fast_tanh(cst);
      ((_Float16*)hA[CUR^1])[eoff] = (_Float16)hl;
    }
  };

  auto window = [&](int B, auto slot_tag) {
    constexpr int SLOT = decltype(slot_tag)::value;
    __syncthreads();
    if (B < 62)                            // T14: issue stage load (batch B+2)
      sv = *reinterpret_cast<const uint2*>(h1in + ((size_t)(r0+sr)*512 + (B+2)*8 + sdt)*128 + scq);
    if (B < 63) {                          // project batch B+1 -> preLDS[SLOT^1]
      floatx4 accP[4];
#pragma unroll
      for (int g = 0; g < 4; ++g) { float bb = bias_v[g]; accP[g] = (floatx4){bb,bb,bb,bb}; }
#pragma unroll
      for (int kt = 0; kt < 4; ++kt) {
        half8 af = aF[SLOT^1][kt*64 + lane];
#pragma unroll
        for (int g = 0; g < 4; ++g)
          accP[g] = __builtin_amdgcn_mfma_f32_16x16x32_f16(af, bf[kt][g], accP[g], 0, 0, 0);
      }
#pragma unroll
      for (int reg = 0; reg < 4; ++reg) {
        int m = ((lane>>4)<<2) + reg;
        floatx4 pv = (floatx4){accP[0][reg], accP[1][reg], accP[2][reg], accP[3][reg]};
        *reinterpret_cast<floatx4*>(&preLDS[SLOT^1][(m*128 + en)*4]) = pv;
      }
    }
    core(ic<SLOT*8 + 0>{});
    __syncthreads();
    if (B < 62)                            // T14: LDS-write of stashed batch
      *reinterpret_cast<uint2*>(((_Float16*)aF[SLOT]) + sidx) = sv;
    core(ic<SLOT*8 + 1>{});
    __syncthreads(); core(ic<SLOT*8 + 2>{});
    __syncthreads(); core(ic<SLOT*8 + 3>{});
    __syncthreads(); core(ic<SLOT*8 + 4>{});
    __syncthreads(); core(ic<SLOT*8 + 5>{});
    __syncthreads(); core(ic<SLOT*8 + 6>{});
    __syncthreads(); core(ic<SLOT*8 + 7>{});
  };

  for (int bp = 0; bp < 32; ++bp) {
    window(2*bp,     ic<0>{});
    window(2*bp + 1, ic<1>{});
  }

  // fused head: out[r] = sum_n h_last[r][n]*wlin[n] + blin
  if (lane < 32) head[rb*128 + en] = hl * wl;
  __syncthreads();
  if (tid < 2) {
    float s = blin[0];
    for (int n = 0; n < 128; ++n) s += head[tid*128 + n];
    out[r0 + tid] = s;
  }
}

extern "C" void kernel_launch(void* const* d_in, const int* in_sizes, int n_in,
                              void* d_out, int out_size, void* d_ws, size_t ws_size,
                              hipStream_t stream)
{
  const float* x    = (const float*)d_in[0];
  const float* wih0 = (const float*)d_in[1];
  const float* whh0 = (const float*)d_in[2];
  const float* bih0 = (const float*)d_in[3];
  const float* bhh0 = (const float*)d_in[4];
  const float* wih1 = (const float*)d_in[5];
  const float* whh1 = (const float*)d_in[6];
  const float* bih1 = (const float*)d_in[7];
  const float* bhh1 = (const float*)d_in[8];
  const float* wlin = (const float*)d_in[9];
  const float* blin = (const float*)d_in[10];
  float* out = (float*)d_out;

  char* ws = (char*)d_ws;
  _Float16* w0f = (_Float16*)(ws);               // 196608 B
  _Float16* w1f = (_Float16*)(ws + 196608);      // 262144 B
  float* bias0  = (float*)(ws + 458752);         // 2048 B
  float* bias1  = (float*)(ws + 460800);         // 2048 B
  _Float16* h1  = (_Float16*)(ws + 1048576);     // 64 MB inter-layer buffer

  prep_kernel<<<256, 256, 0, stream>>>(wih0, whh0, bih0, bhh0, wih1, whh1, bih1, bhh1,
                                       w0f, w1f, bias0, bias1);
  lstm_l0<<<256, 512, 0, stream>>>(x, w0f, bias0, h1);
  lstm_l1<<<256, 512, 0, stream>>>(h1, w1f, bias1, wlin, blin, out);
}